// Round 8
// baseline (457.226 us; speedup 1.0000x reference)
//
#include <hip/hip_runtime.h>
#include <math.h>

#define B_ 4
#define NTOK 1537
#define NH 16
#define NROWS 6148      // B_*NTOK
#define RPAD 6272       // 49*128, padded rows
#define KDIM 1024
#define NKPAD 1568      // keys padded to 32-mult for aligned V^T loads

typedef __attribute__((ext_vector_type(8))) short short8;
typedef __attribute__((ext_vector_type(4))) float f32x4;
typedef __attribute__((ext_vector_type(16))) float f32x16;
typedef __attribute__((ext_vector_type(4))) unsigned short ushort4v;
typedef __attribute__((ext_vector_type(4))) unsigned int uint4v;
typedef __attribute__((ext_vector_type(2))) unsigned int uint2v;

__device__ __forceinline__ float bf2f(unsigned short u){
  unsigned int x = ((unsigned int)u) << 16;
  return __uint_as_float(x);
}
__device__ __forceinline__ unsigned short f2bf(float f){
  unsigned int x = __float_as_uint(f);
  x += 0x7fff + ((x >> 16) & 1);   // RNE
  return (unsigned short)(x >> 16);
}
__device__ __forceinline__ unsigned int pack_bf16(float lo, float hi){
  return (unsigned int)f2bf(lo) | ((unsigned int)f2bf(hi) << 16);
}
// pack two f32 -> bf16 pair via round-half-up + byte-perm (3 ops)
__device__ __forceinline__ unsigned int pack_bf16_fast(float lo, float hi){
  unsigned int ue = __float_as_uint(lo) + 0x8000u;
  unsigned int uo = __float_as_uint(hi) + 0x8000u;
  return __builtin_amdgcn_perm(uo, ue, 0x07060302u);  // D = [uo.hi16, ue.hi16]
}
// native v_exp_f32: computes 2^x
__device__ __forceinline__ float fast_exp2(float x){
  return __builtin_amdgcn_exp2f(x);
}
__device__ __forceinline__ void gload_lds16(const void* g, void* l){
  __builtin_amdgcn_global_load_lds((const __attribute__((address_space(1))) unsigned int*)g,
                                   (__attribute__((address_space(3))) unsigned int*)l, 16, 0, 0);
}
__device__ __forceinline__ f32x4 mfma16(short8 a, short8 b, f32x4 c){
  return __builtin_amdgcn_mfma_f32_16x16x32_bf16(a, b, c, 0, 0, 0);
}
__device__ __forceinline__ f32x16 mfma32(short8 a, short8 b, f32x16 c){
  return __builtin_amdgcn_mfma_f32_32x32x16_bf16(a, b, c, 0, 0, 0);
}

// ---------------- conversions ----------------
__global__ __launch_bounds__(256) void cvt_w_kernel(const float* __restrict__ src,
                                                    unsigned short* __restrict__ dst, int n){
  int i = (blockIdx.x*256 + threadIdx.x)*4;
  if (i >= n) return;
  f32x4 v = *(const f32x4*)(src + i);
  ushort4v o;
  #pragma unroll
  for (int j=0;j<4;j++) o[j] = f2bf(v[j]);
  *(ushort4v*)(dst + i) = o;
}

__global__ __launch_bounds__(256) void cvt_x_kernel(const float* __restrict__ x,
                                                    unsigned short* __restrict__ xb){
  size_t i = ((size_t)blockIdx.x*256 + threadIdx.x)*4;
  if (i >= (size_t)RPAD*KDIM) return;
  size_t row = i >> 10;
  ushort4v o;
  if (row < NROWS){
    f32x4 v = *(const f32x4*)(x + i);
    #pragma unroll
    for (int j=0;j<4;j++) o[j] = f2bf(v[j]);
  } else {
    o = (ushort4v)0;
  }
  *(ushort4v*)(xb + i) = o;
}

// ---------------- RoPE tables (pos 0..12, 32 freqs) ----------------
__global__ void rope_tables_kernel(float* __restrict__ ct, float* __restrict__ st){
  int i = threadIdx.x;
  if (i >= 13*32) return;
  int p = i >> 5, j = i & 31;
  float th = powf(10000.f, -(float)j * (1.f/32.f));
  float ang = (float)p * th;
  ct[i] = cosf(ang);
  st[i] = sinf(ang);
}

// ---------------- stable argsort -> pos table ----------------
// grid (B_, 6): each block ranks 256 elements of one batch.
__global__ __launch_bounds__(256) void argsort_kernel(const int* __restrict__ ids,
                                                      int* __restrict__ postab){
  __shared__ int vals[1536];
  int b = blockIdx.x;
  const int* src = ids + b*1536;
  for (int i=threadIdx.x; i<1536; i+=256) vals[i] = src[i];
  __syncthreads();
  int i = blockIdx.y*256 + threadIdx.x;
  int v = vals[i];
  int rank = 0;
  for (int j=0;j<1536;j++){
    int u = vals[j];
    rank += (u < v) || (u == v && j < i);   // stable rank
  }
  postab[b*1536 + rank] = (i % 12) + 1;     // (p % V) + 1
}

// ---------------- RoPE apply, in-place on bf16 qkv (q and k parts) ----------------
__global__ __launch_bounds__(256) void rope_kernel(unsigned short* __restrict__ qkv,
                                                   const int* __restrict__ postab,
                                                   const float* __restrict__ ct,
                                                   const float* __restrict__ st){
  int idx = blockIdx.x*256 + threadIdx.x;
  if (idx >= B_*NTOK*NH) return;
  int h = idx & 15;
  int bn = idx >> 4;
  int b = bn / NTOK;
  int n = bn - b*NTOK;
  unsigned short* rowp = qkv + (size_t)bn*3072;
  int pos = (n == 0) ? 0 : postab[b*1536 + (n-1)];
  const float* cr = ct + pos*32;
  const float* sr = st + pos*32;
  #pragma unroll
  for (int part=0; part<2; part++){
    unsigned short* p = rowp + part*1024 + h*64;
    uint4v vv[8];
    #pragma unroll
    for (int i=0;i<8;i++) vv[i] = ((const uint4v*)p)[i];
    unsigned short* tp = (unsigned short*)vv;
    unsigned short ov[64];
    if (n == 0){
      #pragma unroll
      for (int j=0;j<32;j++){ ov[j] = tp[2*j]; ov[32+j] = tp[2*j+1]; }
    } else {
      #pragma unroll
      for (int j=0;j<32;j++){
        float re = bf2f(tp[2*j]), im = bf2f(tp[2*j+1]);
        float c = cr[j], s = sr[j];
        ov[j]    = f2bf(re*c - im*s);
        ov[32+j] = f2bf(re*s + im*c);
      }
    }
    #pragma unroll
    for (int i=0;i<8;i++) ((uint4v*)p)[i] = ((const uint4v*)ov)[i];
  }
}

// ---------------- bf16 MFMA GEMM body: out[r][c] = (sum_k A[r][k]*W[c][k] + bias[c]) * scale
__device__ __forceinline__ void gemm_body(const unsigned short* __restrict__ A, int lda,
    const unsigned short* __restrict__ W,
    const float* __restrict__ bias, float scale,
    unsigned short* __restrict__ outb, float* __restrict__ outf, int ldo, int mvalid,
    int rowBase, int colBase)
{
  __shared__ alignas(16) unsigned short At[128][32];
  __shared__ alignas(16) unsigned short Bt[128][32];
  int t = threadIdx.x, w = t >> 6, lane = t & 63;
  int g = lane >> 4, l15 = lane & 15;
  int rb = (w >> 1) * 64, cb = (w & 1) * 64;
  f32x4 acc[4][4];
  #pragma unroll
  for (int m=0;m<4;m++)
    #pragma unroll
    for (int n=0;n<4;n++) acc[m][n] = 0.f;
  int srow = lane >> 2;            // 0..15
  int scol = (lane & 3) * 8;       // 0,8,16,24
  for (int kb = 0; kb < KDIM; kb += 32){
    __syncthreads();
    #pragma unroll
    for (int i=0;i<2;i++){
      int rr = i*64 + w*16 + srow;
      gload_lds16(A + (size_t)(rowBase + rr)*lda + kb + scol, &At[i*64 + w*16][0]);
      gload_lds16(W + (size_t)(colBase + rr)*KDIM + kb + scol, &Bt[i*64 + w*16][0]);
    }
    __syncthreads();
    short8 af[4], bf[4];
    #pragma unroll
    for (int m=0;m<4;m++) af[m] = *(const short8*)&At[rb + m*16 + l15][g*8];
    #pragma unroll
    for (int n=0;n<4;n++) bf[n] = *(const short8*)&Bt[cb + n*16 + l15][g*8];
    #pragma unroll
    for (int m=0;m<4;m++)
      #pragma unroll
      for (int n=0;n<4;n++)
        acc[m][n] = mfma16(af[m], bf[n], acc[m][n]);
  }
  #pragma unroll
  for (int m=0;m<4;m++)
    #pragma unroll
    for (int n=0;n<4;n++){
      int col = colBase + cb + n*16 + l15;
      float bv = bias ? bias[col] : 0.f;
      #pragma unroll
      for (int r=0;r<4;r++){
        int row = rowBase + rb + m*16 + g*4 + r;
        if (row < mvalid){
          float v = (acc[m][n][r] + bv) * scale;
          if (outf) outf[(size_t)row*ldo + col] = v;
          else      outb[(size_t)row*ldo + col] = f2bf(v);
        }
      }
    }
}

__global__ __launch_bounds__(256) void gemm_kernel(const unsigned short* __restrict__ A, int lda,
    const unsigned short* __restrict__ W,
    const float* __restrict__ bias, float scale,
    unsigned short* __restrict__ outb, float* __restrict__ outf, int ldo, int mvalid)
{
  gemm_body(A, lda, W, bias, scale, outb, outf, ldo, mvalid,
            blockIdx.x*128, blockIdx.y*128);
}

// merged in_proj: z = 0,1,2 -> q,k,v
// q scale folds 1/sqrt(64) AND log2(e) (softmax runs in exp2 domain).
__global__ __launch_bounds__(256) void gemm_inproj_kernel(const unsigned short* __restrict__ qkvb,
    const unsigned short* __restrict__ ipwb, const float* __restrict__ ipb,
    unsigned short* __restrict__ qpb, unsigned short* __restrict__ kpb,
    unsigned short* __restrict__ vpb)
{
  int z = blockIdx.z;
  const unsigned short* A = qkvb + z*1024;
  const unsigned short* W = ipwb + (size_t)z*1024*1024;
  const float* bias = ipb + z*1024;
  float scale = (z == 0) ? 0.125f*1.44269504f : 1.f;
  unsigned short* outb = (z == 0) ? qpb : (z == 1 ? kpb : vpb);
  gemm_body(A, 3072, W, bias, scale, outb, nullptr, 1024, NROWS,
            blockIdx.x*128, blockIdx.y*128);
}

// ---------------- V transpose: vp[b*NTOK+n][h*64+e] -> vt[((b*16+h)*64+e)][NKPAD keys]
__global__ __launch_bounds__(256) void vtrans_kernel(const unsigned short* __restrict__ vp,
                                                     unsigned short* __restrict__ vt){
  __shared__ alignas(16) unsigned short Tl[64][72];
  int tile = blockIdx.x, head = blockIdx.y, b = blockIdx.z;
  int t = threadIdx.x;
  {
    int r = t >> 2, ch = t & 3;
    int tok = tile*64 + r;
    uint4v v0, v1;
    if (tok < NTOK){
      const unsigned short* src = vp + (size_t)(b*NTOK + tok)*KDIM + head*64 + ch*16;
      v0 = *(const uint4v*)src;
      v1 = *(const uint4v*)(src + 8);
    } else { v0 = (uint4v)0; v1 = (uint4v)0; }
    *(uint4v*)&Tl[r][ch*16]     = v0;
    *(uint4v*)&Tl[r][ch*16 + 8] = v1;
  }
  __syncthreads();
  {
    int c = t & 63, rchunk = t >> 6;
    int tokBase = tile*64 + rchunk*16;
    if (tokBase < NKPAD){
      unsigned short ov[16];
      #pragma unroll
      for (int j=0;j<16;j++) ov[j] = Tl[rchunk*16 + j][c];
      unsigned short* dst = vt + ((size_t)(((b*16 + head) << 6) + c))*NKPAD + tokBase;
      *(uint4v*)dst       = *(const uint4v*)&ov[0];
      *(uint4v*)(dst + 8) = *(const uint4v*)&ov[8];
    }
  }
}

// ---------------- flash attention, 32x32x16 MFMA, swapped operands, zero LDS,
// 2-deep pipeline (QK of tile kt+1 issued before softmax of tile kt), exp2 softmax.
// grid (B*H, 13); 4 waves, each owns 32 q rows.
// Layouts (32x32x16): A row = l&31, k = (l>>5)*8+j ; B col = l&31 ;
// C/D col = l&31, row(key/d) = (reg&3) + 8*(reg>>2) + 4*(l>>5)
__global__ __launch_bounds__(256) void attn_kernel(const unsigned short* __restrict__ qp,
    const unsigned short* __restrict__ kp, const unsigned short* __restrict__ vt,
    unsigned short* __restrict__ ctx)
{
  int bh = blockIdx.x;
  int qt = blockIdx.y;
  int b = bh >> 4, hd = bh & 15;
  int t = threadIdx.x, w = t >> 6, lane = t & 63;
  int l31 = lane & 31, hh = lane >> 5;
  int qrow = qt*128 + w*32 + l31;
  int qcl = qrow > NTOK-1 ? NTOK-1 : qrow;
  const unsigned short* qb = qp + (((size_t)(b*NTOK + qcl)*NH + hd) << 6) + hh*8;
  short8 qf[4];
  #pragma unroll
  for (int c=0;c<4;c++) qf[c] = *(const short8*)(qb + c*16);
  const unsigned short* kptr = kp + (((size_t)(b*NTOK + l31)*NH + hd) << 6) + hh*8;
  const unsigned short* vptr = vt + ((size_t)(bh*64 + l31))*NKPAD + hh*8;
  float m_ = -3e38f, l_ = 0.f;
  f32x16 o0 = 0.f, o1 = 0.f;

  auto soft_pv = [&](f32x16 cc, short8 va00, short8 va01, short8 va10, short8 va11){
    float t0 = fmaxf(fmaxf(cc[0],cc[1]), fmaxf(cc[2],cc[3]));
    float t1 = fmaxf(fmaxf(cc[4],cc[5]), fmaxf(cc[6],cc[7]));
    float t2 = fmaxf(fmaxf(cc[8],cc[9]), fmaxf(cc[10],cc[11]));
    float t3 = fmaxf(fmaxf(cc[12],cc[13]), fmaxf(cc[14],cc[15]));
    float mx = fmaxf(fmaxf(t0,t1), fmaxf(t2,t3));
    mx = fmaxf(mx, __shfl_xor(mx, 32));
    // defer-max (T13): 11.5 log2-units ~= 8 nats; P bounded by 2^11.5
    if (!__all(mx <= m_ + 11.5f)){
      float mn = fmaxf(m_, mx);
      float al = fast_exp2(m_ - mn);
      m_ = mn;
      l_ *= al;
      #pragma unroll
      for (int i=0;i<16;i++){ o0[i] *= al; o1[i] *= al; }
    }
    float p[16], rs = 0.f;
    #pragma unroll
    for (int i=0;i<16;i++){ p[i] = fast_exp2(cc[i] - m_); }
    #pragma unroll
    for (int i=0;i<16;i++) rs += p[i];
    rs += __shfl_xor(rs, 32);
    l_ += rs;
    // pack P: W[wd] = keys (2wd, 2wd+1) for q=l31 (round-half-up + byte-perm)
    unsigned int W[8];
    #pragma unroll
    for (int wd=0; wd<8; wd++) W[wd] = pack_bf16_fast(p[2*wd], p[2*wd+1]);
    // cross-half exchange: partner's complementary words
    unsigned int Y0 = (unsigned int)__shfl_xor((int)(hh ? W[0] : W[2]), 32);
    unsigned int Y1 = (unsigned int)__shfl_xor((int)(hh ? W[1] : W[3]), 32);
    unsigned int Y2 = (unsigned int)__shfl_xor((int)(hh ? W[4] : W[6]), 32);
    unsigned int Y3 = (unsigned int)__shfl_xor((int)(hh ? W[5] : W[7]), 32);
    uint4v u0, u1;
    if (hh){ u0[0]=Y0; u0[1]=Y1; u0[2]=W[2]; u0[3]=W[3];
             u1[0]=Y2; u1[1]=Y3; u1[2]=W[6]; u1[3]=W[7]; }
    else   { u0[0]=W[0]; u0[1]=W[1]; u0[2]=Y0; u0[3]=Y1;
             u1[0]=W[4]; u1[1]=W[5]; u1[2]=Y2; u1[3]=Y3; }
    short8 pb0, pb1;
    __builtin_memcpy(&pb0, &u0, 16);
    __builtin_memcpy(&pb1, &u1, 16);
    o0 = mfma32(va00, pb0, o0);
    o0 = mfma32(va01, pb1, o0);
    o1 = mfma32(va10, pb0, o1);
    o1 = mfma32(va11, pb1, o1);
  };

  // prologue: cc(tile 0), K(tile 1) in flight
  short8 ka[4];
  #pragma unroll
  for (int c=0;c<4;c++) ka[c] = *(const short8*)(kptr + c*16);
  kptr += (size_t)32*NH*64;
  f32x16 cc = 0.f;
  cc = mfma32(ka[0], qf[0], cc);
  cc = mfma32(ka[1], qf[1], cc);
  cc = mfma32(ka[2], qf[2], cc);
  cc = mfma32(ka[3], qf[3], cc);
  #pragma unroll
  for (int c=0;c<4;c++) ka[c] = *(const short8*)(kptr + c*16);
  kptr += (size_t)32*NH*64;

  for (int kt=0; kt<48; ++kt){
    // V for tile kt, issued first
    const unsigned short* vB = vptr + kt*32;
    short8 va00 = *(const short8*)(vB);
    short8 va01 = *(const short8*)(vB + 16);
    short8 va10 = *(const short8*)(vB + (size_t)32*NKPAD);
    short8 va11 = *(const short8*)(vB + (size_t)32*NKPAD + 16);
    // QK^T for tile kt+1 — executes in the MFMA pipe during soft_pv(kt)'s VALU work.
    // kt=47 computes tile 48 (tail) from over-read rows: in-allocation, masked below.
    f32x16 cn = 0.f;
    cn = mfma32(ka[0], qf[0], cn);
    cn = mfma32(ka[1], qf[1], cn);
    cn = mfma32(ka[2], qf[2], cn);
    cn = mfma32(ka[3], qf[3], cn);
    // prefetch K for tile kt+2 (over-reads tiles 48/49: rows < RPAD, never consumed)
    #pragma unroll
    for (int c=0;c<4;c++) ka[c] = *(const short8*)(kptr + c*16);
    kptr += (size_t)32*NH*64;
    soft_pv(cc, va00, va01, va10, va11);
    cc = cn;
  }
  // tail tile 48: only key 1536 valid -> (reg 0, hh 0)
  {
    const unsigned short* vB = vptr + 48*32;
    short8 va00 = *(const short8*)(vB);
    short8 va01 = *(const short8*)(vB + 16);
    short8 va10 = *(const short8*)(vB + (size_t)32*NKPAD);
    short8 va11 = *(const short8*)(vB + (size_t)32*NKPAD + 16);
    #pragma unroll
    for (int i=0;i<16;i++) cc[i] = (i == 0 && hh == 0) ? cc[i] : -1e30f;
    soft_pv(cc, va00, va01, va10, va11);
  }
  // write: o{0,1}[reg] -> ctx[q=l31][d = dblk*32 + 8*(reg>>2) + 4*hh + (reg&3)]
  if (qrow < NTOK){
    float inv = 1.f / l_;
    unsigned short* cb = ctx + (((size_t)(b*NTOK + qrow)*NH + hd) << 6) + 4*hh;
    #pragma unroll
    for (int s=0;s<4;s++){
      uint2v u;
      u[0] = pack_bf16(o0[4*s]*inv,   o0[4*s+1]*inv);
      u[1] = pack_bf16(o0[4*s+2]*inv, o0[4*s+3]*inv);
      *(uint2v*)(cb + 8*s) = u;
    }
    #pragma unroll
    for (int s=0;s<4;s++){
      uint2v u;
      u[0] = pack_bf16(o1[4*s]*inv,   o1[4*s+1]*inv);
      u[1] = pack_bf16(o1[4*s+2]*inv, o1[4*s+3]*inv);
      *(uint2v*)(cb + 32 + 8*s) = u;
    }
  }
}

extern "C" void kernel_launch(void* const* d_in, const int* in_sizes, int n_in,
                              void* d_out, int out_size, void* d_ws, size_t ws_size,
                              hipStream_t stream)
{
  const float* x    = (const float*)d_in[0];
  const float* qkvw = (const float*)d_in[1];
  const float* ipw  = (const float*)d_in[2];
  const float* ipb  = (const float*)d_in[3];
  const float* opw  = (const float*)d_in[4];
  const float* opb  = (const float*)d_in[5];
  const float* pw   = (const float*)d_in[6];
  const float* pb   = (const float*)d_in[7];
  const int*   ids  = (const int*)d_in[8];
  float* out = (float*)d_out;

  char* p = (char*)d_ws;
  auto alloc = [&](size_t bytes)->char* {
    char* r = p; p += (bytes + 255) & ~(size_t)255; return r;
  };
  unsigned short* xb    = (unsigned short*)alloc((size_t)RPAD*1024*2);   // reused as vt
  unsigned short* qkvwb = (unsigned short*)alloc((size_t)3072*1024*2);
  unsigned short* ipwb  = (unsigned short*)alloc((size_t)3072*1024*2);
  unsigned short* opwb  = (unsigned short*)alloc((size_t)1024*1024*2);
  unsigned short* pwb   = (unsigned short*)alloc((size_t)1024*1024*2);
  unsigned short* qkvb  = (unsigned short*)alloc((size_t)RPAD*3072*2);
  unsigned short* qpb   = (unsigned short*)alloc((size_t)RPAD*1024*2);
  unsigned short* kpb   = (unsigned short*)alloc((size_t)RPAD*1024*2);
  unsigned short* vpb   = (unsigned short*)alloc((size_t)RPAD*1024*2);
  unsigned short* ctxb  = (unsigned short*)alloc((size_t)RPAD*1024*2);
  unsigned short* mhab  = (unsigned short*)alloc((size_t)RPAD*1024*2);
  int*   postab = (int*)alloc((size_t)B_*1536*4);
  float* ctab   = (float*)alloc(13*32*4);
  float* stab   = (float*)alloc(13*32*4);
  unsigned short* vtb = xb;   // alias: xb (12,845,056 B) == vt (4096*NKPAD*2)

  cvt_w_kernel<<<3072, 256, 0, stream>>>(qkvw, qkvwb, 3072*1024);
  cvt_w_kernel<<<3072, 256, 0, stream>>>(ipw,  ipwb,  3072*1024);
  cvt_w_kernel<<<1024, 256, 0, stream>>>(opw,  opwb,  1024*1024);
  cvt_w_kernel<<<1024, 256, 0, stream>>>(pw,   pwb,   1024*1024);
  cvt_x_kernel<<<RPAD, 256, 0, stream>>>(x, xb);
  rope_tables_kernel<<<1, 512, 0, stream>>>(ctab, stab);
  argsort_kernel<<<dim3(B_, 6), 256, 0, stream>>>(ids, postab);

  // qkv = x @ qkv_w^T  (no bias), bf16 out
  gemm_kernel<<<dim3(RPAD/128, 3072/128), 256, 0, stream>>>(xb, 1024, qkvwb, nullptr, 1.f,
                                                            qkvb, nullptr, 3072, NROWS);
  // RoPE in place on q,k
  rope_kernel<<<(B_*NTOK*NH + 255)/256, 256, 0, stream>>>(qkvb, postab, ctab, stab);
  // in_proj merged: qp (*0.125*log2e folded), kp, vp
  gemm_inproj_kernel<<<dim3(RPAD/128, 8, 3), 256, 0, stream>>>(qkvb, ipwb, ipb, qpb, kpb, vpb);
  // V transpose into vt (aliases dead xb)
  vtrans_kernel<<<dim3(25, 16, 4), 256, 0, stream>>>(vpb, vtb);
  // attention
  attn_kernel<<<dim3(B_*NH, 13), 256, 0, stream>>>(qpb, kpb, vtb, ctxb);
  // out_proj then proj (final f32 to d_out)
  gemm_kernel<<<dim3(RPAD/128, 8), 256, 0, stream>>>(ctxb, 1024, opwb, opb, 1.f,
                                                     mhab, nullptr, 1024, NROWS);
  gemm_kernel<<<dim3(RPAD/128, 8), 256, 0, stream>>>(mhab, 1024, pwb,  pb,  1.f,
                                                     nullptr, out, 1024, NROWS);
}

// Round 9
// 457.102 us; speedup vs baseline: 1.0003x; 1.0003x over previous
//
#include <hip/hip_runtime.h>
#include <math.h>

#define B_ 4
#define NTOK 1537
#define NH 16
#define NROWS 6148      // B_*NTOK
#define RPAD 6272       // 49*128, padded rows
#define KDIM 1024
#define NKPAD 1568      // keys padded to 32-mult for aligned V^T loads

typedef __attribute__((ext_vector_type(8))) short short8;
typedef __attribute__((ext_vector_type(4))) float f32x4;
typedef __attribute__((ext_vector_type(16))) float f32x16;
typedef __attribute__((ext_vector_type(4))) unsigned short ushort4v;
typedef __attribute__((ext_vector_type(4))) unsigned int uint4v;
typedef __attribute__((ext_vector_type(2))) unsigned int uint2v;

__device__ __forceinline__ float bf2f(unsigned short u){
  unsigned int x = ((unsigned int)u) << 16;
  return __uint_as_float(x);
}
__device__ __forceinline__ unsigned short f2bf(float f){
  unsigned int x = __float_as_uint(f);
  x += 0x7fff + ((x >> 16) & 1);   // RNE
  return (unsigned short)(x >> 16);
}
__device__ __forceinline__ unsigned int pack_bf16(float lo, float hi){
  return (unsigned int)f2bf(lo) | ((unsigned int)f2bf(hi) << 16);
}
// pack two f32 -> bf16 pair via round-half-up + byte-perm (3 ops)
__device__ __forceinline__ unsigned int pack_bf16_fast(float lo, float hi){
  unsigned int ue = __float_as_uint(lo) + 0x8000u;
  unsigned int uo = __float_as_uint(hi) + 0x8000u;
  return __builtin_amdgcn_perm(uo, ue, 0x07060302u);  // D = [uo.hi16, ue.hi16]
}
// native v_exp_f32: computes 2^x
__device__ __forceinline__ float fast_exp2(float x){
  return __builtin_amdgcn_exp2f(x);
}
// v_permlane32_swap_b32: returns ( {a.lo32lanes, b.lo32lanes}, {a.hi32lanes, b.hi32lanes} )
__device__ __forceinline__ uint2v permswap(unsigned int a, unsigned int b){
  return __builtin_amdgcn_permlane32_swap(a, b, false, false);
}
__device__ __forceinline__ void gload_lds16(const void* g, void* l){
  __builtin_amdgcn_global_load_lds((const __attribute__((address_space(1))) unsigned int*)g,
                                   (__attribute__((address_space(3))) unsigned int*)l, 16, 0, 0);
}
__device__ __forceinline__ f32x4 mfma16(short8 a, short8 b, f32x4 c){
  return __builtin_amdgcn_mfma_f32_16x16x32_bf16(a, b, c, 0, 0, 0);
}
__device__ __forceinline__ f32x16 mfma32(short8 a, short8 b, f32x16 c){
  return __builtin_amdgcn_mfma_f32_32x32x16_bf16(a, b, c, 0, 0, 0);
}

// ---------------- conversions ----------------
__global__ __launch_bounds__(256) void cvt_w_kernel(const float* __restrict__ src,
                                                    unsigned short* __restrict__ dst, int n){
  int i = (blockIdx.x*256 + threadIdx.x)*4;
  if (i >= n) return;
  f32x4 v = *(const f32x4*)(src + i);
  ushort4v o;
  #pragma unroll
  for (int j=0;j<4;j++) o[j] = f2bf(v[j]);
  *(ushort4v*)(dst + i) = o;
}

__global__ __launch_bounds__(256) void cvt_x_kernel(const float* __restrict__ x,
                                                    unsigned short* __restrict__ xb){
  size_t i = ((size_t)blockIdx.x*256 + threadIdx.x)*4;
  if (i >= (size_t)RPAD*KDIM) return;
  size_t row = i >> 10;
  ushort4v o;
  if (row < NROWS){
    f32x4 v = *(const f32x4*)(x + i);
    #pragma unroll
    for (int j=0;j<4;j++) o[j] = f2bf(v[j]);
  } else {
    o = (ushort4v)0;
  }
  *(ushort4v*)(xb + i) = o;
}

// ---------------- RoPE tables (pos 0..12, 32 freqs) ----------------
__global__ void rope_tables_kernel(float* __restrict__ ct, float* __restrict__ st){
  int i = threadIdx.x;
  if (i >= 13*32) return;
  int p = i >> 5, j = i & 31;
  float th = powf(10000.f, -(float)j * (1.f/32.f));
  float ang = (float)p * th;
  ct[i] = cosf(ang);
  st[i] = sinf(ang);
}

// ---------------- stable argsort -> pos table ----------------
// grid (B_, 6): each block ranks 256 elements of one batch.
__global__ __launch_bounds__(256) void argsort_kernel(const int* __restrict__ ids,
                                                      int* __restrict__ postab){
  __shared__ int vals[1536];
  int b = blockIdx.x;
  const int* src = ids + b*1536;
  for (int i=threadIdx.x; i<1536; i+=256) vals[i] = src[i];
  __syncthreads();
  int i = blockIdx.y*256 + threadIdx.x;
  int v = vals[i];
  int rank = 0;
  for (int j=0;j<1536;j++){
    int u = vals[j];
    rank += (u < v) || (u == v && j < i);   // stable rank
  }
  postab[b*1536 + rank] = (i % 12) + 1;     // (p % V) + 1
}

// ---------------- RoPE apply, in-place on bf16 qkv (q and k parts) ----------------
__global__ __launch_bounds__(256) void rope_kernel(unsigned short* __restrict__ qkv,
                                                   const int* __restrict__ postab,
                                                   const float* __restrict__ ct,
                                                   const float* __restrict__ st){
  int idx = blockIdx.x*256 + threadIdx.x;
  if (idx >= B_*NTOK*NH) return;
  int h = idx & 15;
  int bn = idx >> 4;
  int b = bn / NTOK;
  int n = bn - b*NTOK;
  unsigned short* rowp = qkv + (size_t)bn*3072;
  int pos = (n == 0) ? 0 : postab[b*1536 + (n-1)];
  const float* cr = ct + pos*32;
  const float* sr = st + pos*32;
  #pragma unroll
  for (int part=0; part<2; part++){
    unsigned short* p = rowp + part*1024 + h*64;
    uint4v vv[8];
    #pragma unroll
    for (int i=0;i<8;i++) vv[i] = ((const uint4v*)p)[i];
    unsigned short* tp = (unsigned short*)vv;
    unsigned short ov[64];
    if (n == 0){
      #pragma unroll
      for (int j=0;j<32;j++){ ov[j] = tp[2*j]; ov[32+j] = tp[2*j+1]; }
    } else {
      #pragma unroll
      for (int j=0;j<32;j++){
        float re = bf2f(tp[2*j]), im = bf2f(tp[2*j+1]);
        float c = cr[j], s = sr[j];
        ov[j]    = f2bf(re*c - im*s);
        ov[32+j] = f2bf(re*s + im*c);
      }
    }
    #pragma unroll
    for (int i=0;i<8;i++) ((uint4v*)p)[i] = ((const uint4v*)ov)[i];
  }
}

// ---------------- bf16 MFMA GEMM body: out[r][c] = (sum_k A[r][k]*W[c][k] + bias[c]) * scale
__device__ __forceinline__ void gemm_body(const unsigned short* __restrict__ A, int lda,
    const unsigned short* __restrict__ W,
    const float* __restrict__ bias, float scale,
    unsigned short* __restrict__ outb, float* __restrict__ outf, int ldo, int mvalid,
    int rowBase, int colBase)
{
  __shared__ alignas(16) unsigned short At[128][32];
  __shared__ alignas(16) unsigned short Bt[128][32];
  int t = threadIdx.x, w = t >> 6, lane = t & 63;
  int g = lane >> 4, l15 = lane & 15;
  int rb = (w >> 1) * 64, cb = (w & 1) * 64;
  f32x4 acc[4][4];
  #pragma unroll
  for (int m=0;m<4;m++)
    #pragma unroll
    for (int n=0;n<4;n++) acc[m][n] = 0.f;
  int srow = lane >> 2;            // 0..15
  int scol = (lane & 3) * 8;       // 0,8,16,24
  for (int kb = 0; kb < KDIM; kb += 32){
    __syncthreads();
    #pragma unroll
    for (int i=0;i<2;i++){
      int rr = i*64 + w*16 + srow;
      gload_lds16(A + (size_t)(rowBase + rr)*lda + kb + scol, &At[i*64 + w*16][0]);
      gload_lds16(W + (size_t)(colBase + rr)*KDIM + kb + scol, &Bt[i*64 + w*16][0]);
    }
    __syncthreads();
    short8 af[4], bf[4];
    #pragma unroll
    for (int m=0;m<4;m++) af[m] = *(const short8*)&At[rb + m*16 + l15][g*8];
    #pragma unroll
    for (int n=0;n<4;n++) bf[n] = *(const short8*)&Bt[cb + n*16 + l15][g*8];
    #pragma unroll
    for (int m=0;m<4;m++)
      #pragma unroll
      for (int n=0;n<4;n++)
        acc[m][n] = mfma16(af[m], bf[n], acc[m][n]);
  }
  #pragma unroll
  for (int m=0;m<4;m++)
    #pragma unroll
    for (int n=0;n<4;n++){
      int col = colBase + cb + n*16 + l15;
      float bv = bias ? bias[col] : 0.f;
      #pragma unroll
      for (int r=0;r<4;r++){
        int row = rowBase + rb + m*16 + g*4 + r;
        if (row < mvalid){
          float v = (acc[m][n][r] + bv) * scale;
          if (outf) outf[(size_t)row*ldo + col] = v;
          else      outb[(size_t)row*ldo + col] = f2bf(v);
        }
      }
    }
}

__global__ __launch_bounds__(256) void gemm_kernel(const unsigned short* __restrict__ A, int lda,
    const unsigned short* __restrict__ W,
    const float* __restrict__ bias, float scale,
    unsigned short* __restrict__ outb, float* __restrict__ outf, int ldo, int mvalid)
{
  gemm_body(A, lda, W, bias, scale, outb, outf, ldo, mvalid,
            blockIdx.x*128, blockIdx.y*128);
}

// merged in_proj: z = 0,1,2 -> q,k,v
// q scale folds 1/sqrt(64) AND log2(e) (softmax runs in exp2 domain).
__global__ __launch_bounds__(256) void gemm_inproj_kernel(const unsigned short* __restrict__ qkvb,
    const unsigned short* __restrict__ ipwb, const float* __restrict__ ipb,
    unsigned short* __restrict__ qpb, unsigned short* __restrict__ kpb,
    unsigned short* __restrict__ vpb)
{
  int z = blockIdx.z;
  const unsigned short* A = qkvb + z*1024;
  const unsigned short* W = ipwb + (size_t)z*1024*1024;
  const float* bias = ipb + z*1024;
  float scale = (z == 0) ? 0.125f*1.44269504f : 1.f;
  unsigned short* outb = (z == 0) ? qpb : (z == 1 ? kpb : vpb);
  gemm_body(A, 3072, W, bias, scale, outb, nullptr, 1024, NROWS,
            blockIdx.x*128, blockIdx.y*128);
}

// ---------------- V transpose: vp[b*NTOK+n][h*64+e] -> vt[((b*16+h)*64+e)][NKPAD keys]
__global__ __launch_bounds__(256) void vtrans_kernel(const unsigned short* __restrict__ vp,
                                                     unsigned short* __restrict__ vt){
  __shared__ alignas(16) unsigned short Tl[64][72];
  int tile = blockIdx.x, head = blockIdx.y, b = blockIdx.z;
  int t = threadIdx.x;
  {
    int r = t >> 2, ch = t & 3;
    int tok = tile*64 + r;
    uint4v v0, v1;
    if (tok < NTOK){
      const unsigned short* src = vp + (size_t)(b*NTOK + tok)*KDIM + head*64 + ch*16;
      v0 = *(const uint4v*)src;
      v1 = *(const uint4v*)(src + 8);
    } else { v0 = (uint4v)0; v1 = (uint4v)0; }
    *(uint4v*)&Tl[r][ch*16]     = v0;
    *(uint4v*)&Tl[r][ch*16 + 8] = v1;
  }
  __syncthreads();
  {
    int c = t & 63, rchunk = t >> 6;
    int tokBase = tile*64 + rchunk*16;
    if (tokBase < NKPAD){
      unsigned short ov[16];
      #pragma unroll
      for (int j=0;j<16;j++) ov[j] = Tl[rchunk*16 + j][c];
      unsigned short* dst = vt + ((size_t)(((b*16 + head) << 6) + c))*NKPAD + tokBase;
      *(uint4v*)dst       = *(const uint4v*)&ov[0];
      *(uint4v*)(dst + 8) = *(const uint4v*)&ov[8];
    }
  }
}

// ---------------- flash attention, 32x32x16 MFMA, swapped operands, zero LDS,
// 2-deep pipeline, exp2 softmax, ALL cross-lane via v_permlane32_swap (no DS ops).
// grid (B*H, 13); 4 waves, each owns 32 q rows.
// Layouts (32x32x16): A row = l&31, k = (l>>5)*8+j ; B col = l&31 ;
// C/D col = l&31, row(key/d) = (reg&3) + 8*(reg>>2) + 4*(l>>5)
__global__ __launch_bounds__(256) void attn_kernel(const unsigned short* __restrict__ qp,
    const unsigned short* __restrict__ kp, const unsigned short* __restrict__ vt,
    unsigned short* __restrict__ ctx)
{
  int bh = blockIdx.x;
  int qt = blockIdx.y;
  int b = bh >> 4, hd = bh & 15;
  int t = threadIdx.x, w = t >> 6, lane = t & 63;
  int l31 = lane & 31, hh = lane >> 5;
  int qrow = qt*128 + w*32 + l31;
  int qcl = qrow > NTOK-1 ? NTOK-1 : qrow;
  const unsigned short* qb = qp + (((size_t)(b*NTOK + qcl)*NH + hd) << 6) + hh*8;
  short8 qf[4];
  #pragma unroll
  for (int c=0;c<4;c++) qf[c] = *(const short8*)(qb + c*16);
  const unsigned short* kptr = kp + (((size_t)(b*NTOK + l31)*NH + hd) << 6) + hh*8;
  const unsigned short* vptr = vt + ((size_t)(bh*64 + l31))*NKPAD + hh*8;
  float m_ = -3e38f, l_ = 0.f;   // l_ is a PER-HALF partial sum; reduced once at the end
  f32x16 o0 = 0.f, o1 = 0.f;

  auto soft_pv = [&](f32x16 cc, short8 va00, short8 va01, short8 va10, short8 va11){
    float t0 = fmaxf(fmaxf(cc[0],cc[1]), fmaxf(cc[2],cc[3]));
    float t1 = fmaxf(fmaxf(cc[4],cc[5]), fmaxf(cc[6],cc[7]));
    float t2 = fmaxf(fmaxf(cc[8],cc[9]), fmaxf(cc[10],cc[11]));
    float t3 = fmaxf(fmaxf(cc[12],cc[13]), fmaxf(cc[14],cc[15]));
    float mx = fmaxf(fmaxf(t0,t1), fmaxf(t2,t3));
    {   // cross-half max via permlane (VALU, no DS)
      uint2v pr = permswap(__float_as_uint(mx), __float_as_uint(mx));
      mx = fmaxf(__uint_as_float(pr[0]), __uint_as_float(pr[1]));
    }
    // defer-max (T13): 11.5 log2-units ~= 8 nats; P bounded by 2^11.5
    if (!__all(mx <= m_ + 11.5f)){
      float mn = fmaxf(m_, mx);
      float al = fast_exp2(m_ - mn);
      m_ = mn;
      l_ *= al;
      #pragma unroll
      for (int i=0;i<16;i++){ o0[i] *= al; o1[i] *= al; }
    }
    float p[16], rs = 0.f;
    #pragma unroll
    for (int i=0;i<16;i++){ p[i] = fast_exp2(cc[i] - m_); }
    #pragma unroll
    for (int i=0;i<16;i++) rs += p[i];
    l_ += rs;   // per-half partial (m_ is synchronized across halves)
    // pack P: W[wd] = keys (8*(wd>>1) + 4*hh + 2*(wd&1) ..+1) for q=l31
    unsigned int W[8];
    #pragma unroll
    for (int wd=0; wd<8; wd++) W[wd] = pack_bf16_fast(p[2*wd], p[2*wd+1]);
    // cross-half exchange via permlane32_swap:
    // e=swap(Wa,Wb): e[0] = {Wa.lo,Wb.lo} (own/partner), e[1] = {Wa.hi,Wb.hi} (partner/own)
    uint2v e0 = permswap(W[0], W[2]);
    uint2v e1 = permswap(W[1], W[3]);
    uint2v e2 = permswap(W[4], W[6]);
    uint2v e3 = permswap(W[5], W[7]);
    uint4v u0, u1;
    u0[0]=e0[0]; u0[1]=e1[0]; u0[2]=e0[1]; u0[3]=e1[1];
    u1[0]=e2[0]; u1[1]=e3[0]; u1[2]=e2[1]; u1[3]=e3[1];
    short8 pb0, pb1;
    __builtin_memcpy(&pb0, &u0, 16);
    __builtin_memcpy(&pb1, &u1, 16);
    o0 = mfma32(va00, pb0, o0);
    o0 = mfma32(va01, pb1, o0);
    o1 = mfma32(va10, pb0, o1);
    o1 = mfma32(va11, pb1, o1);
  };

  // prologue: cc(tile 0), K(tile 1) in flight
  short8 ka[4];
  #pragma unroll
  for (int c=0;c<4;c++) ka[c] = *(const short8*)(kptr + c*16);
  kptr += (size_t)32*NH*64;
  f32x16 cc = 0.f;
  cc = mfma32(ka[0], qf[0], cc);
  cc = mfma32(ka[1], qf[1], cc);
  cc = mfma32(ka[2], qf[2], cc);
  cc = mfma32(ka[3], qf[3], cc);
  #pragma unroll
  for (int c=0;c<4;c++) ka[c] = *(const short8*)(kptr + c*16);
  kptr += (size_t)32*NH*64;

  for (int kt=0; kt<48; ++kt){
    // V for tile kt, issued first
    const unsigned short* vB = vptr + kt*32;
    short8 va00 = *(const short8*)(vB);
    short8 va01 = *(const short8*)(vB + 16);
    short8 va10 = *(const short8*)(vB + (size_t)32*NKPAD);
    short8 va11 = *(const short8*)(vB + (size_t)32*NKPAD + 16);
    // QK^T for tile kt+1 — runs in the MFMA pipe during soft_pv(kt)'s VALU work.
    // kt=47 computes tile 48 (tail) from over-read rows: in-allocation, masked below.
    f32x16 cn = 0.f;
    cn = mfma32(ka[0], qf[0], cn);
    cn = mfma32(ka[1], qf[1], cn);
    cn = mfma32(ka[2], qf[2], cn);
    cn = mfma32(ka[3], qf[3], cn);
    // prefetch K for tile kt+2 (over-reads tiles 48/49: rows < RPAD, never consumed)
    #pragma unroll
    for (int c=0;c<4;c++) ka[c] = *(const short8*)(kptr + c*16);
    kptr += (size_t)32*NH*64;
    soft_pv(cc, va00, va01, va10, va11);
    cc = cn;
  }
  // tail tile 48: only key 1536 valid -> (reg 0, hh 0)
  {
    const unsigned short* vB = vptr + 48*32;
    short8 va00 = *(const short8*)(vB);
    short8 va01 = *(const short8*)(vB + 16);
    short8 va10 = *(const short8*)(vB + (size_t)32*NKPAD);
    short8 va11 = *(const short8*)(vB + (size_t)32*NKPAD + 16);
    #pragma unroll
    for (int i=0;i<16;i++) cc[i] = (i == 0 && hh == 0) ? cc[i] : -1e30f;
    soft_pv(cc, va00, va01, va10, va11);
  }
  // final cross-half l reduce (the only one in the kernel)
  {
    uint2v pr = permswap(__float_as_uint(l_), __float_as_uint(l_));
    l_ = __uint_as_float(pr[0]) + __uint_as_float(pr[1]);
  }
  // write: o{0,1}[reg] -> ctx[q=l31][d = dblk*32 + 8*(reg>>2) + 4*hh + (reg&3)]
  if (qrow < NTOK){
    float inv = 1.f / l_;
    unsigned short* cb = ctx + (((size_t)(b*NTOK + qrow)*NH + hd) << 6) + 4*hh;
    #pragma unroll
    for (int s=0;s<4;s++){
      uint2v u;
      u[0] = pack_bf16(o0[4*s]*inv,   o0[4*s+1]*inv);
      u[1] = pack_bf16(o0[4*s+2]*inv, o0[4*s+3]*inv);
      *(uint2v*)(cb + 8*s) = u;
    }
    #pragma unroll
    for (int s=0;s<4;s++){
      uint2v u;
      u[0] = pack_bf16(o1[4*s]*inv,   o1[4*s+1]*inv);
      u[1] = pack_bf16(o1[4*s+2]*inv, o1[4*s+3]*inv);
      *(uint2v*)(cb + 32 + 8*s) = u;
    }
  }
}

extern "C" void kernel_launch(void* const* d_in, const int* in_sizes, int n_in,
                              void* d_out, int out_size, void* d_ws, size_t ws_size,
                              hipStream_t stream)
{
  const float* x    = (const float*)d_in[0];
  const float* qkvw = (const float*)d_in[1];
  const float* ipw  = (const float*)d_in[2];
  const float* ipb  = (const float*)d_in[3];
  const float* opw  = (const float*)d_in[4];
  const float* opb  = (const float*)d_in[5];
  const float* pw   = (const float*)d_in[6];
  const float* pb   = (const float*)d_in[7];
  const int*   ids  = (const int*)d_in[8];
  float* out = (float*)d_out;

  char* p = (char*)d_ws;
  auto alloc = [&](size_t bytes)->char* {
    char* r = p; p += (bytes + 255) & ~(size_t)255; return r;
  };
  unsigned short* xb    = (unsigned short*)alloc((size_t)RPAD*1024*2);   // reused as vt
  unsigned short* qkvwb = (unsigned short*)alloc((size_t)3072*1024*2);
  unsigned short* ipwb  = (unsigned short*)alloc((size_t)3072*1024*2);
  unsigned short* opwb  = (unsigned short*)alloc((size_t)1024*1024*2);
  unsigned short* pwb   = (unsigned short*)alloc((size_t)1024*1024*2);
  unsigned short* qkvb  = (unsigned short*)alloc((size_t)RPAD*3072*2);
  unsigned short* qpb   = (unsigned short*)alloc((size_t)RPAD*1024*2);
  unsigned short* kpb   = (unsigned short*)alloc((size_t)RPAD*1024*2);
  unsigned short* vpb   = (unsigned short*)alloc((size_t)RPAD*1024*2);
  unsigned short* ctxb  = (unsigned short*)alloc((size_t)RPAD*1024*2);
  unsigned short* mhab  = (unsigned short*)alloc((size_t)RPAD*1024*2);
  int*   postab = (int*)alloc((size_t)B_*1536*4);
  float* ctab   = (float*)alloc(13*32*4);
  float* stab   = (float*)alloc(13*32*4);
  unsigned short* vtb = xb;   // alias: xb (12,845,056 B) == vt (4096*NKPAD*2)

  cvt_w_kernel<<<3072, 256, 0, stream>>>(qkvw, qkvwb, 3072*1024);
  cvt_w_kernel<<<3072, 256, 0, stream>>>(ipw,  ipwb,  3072*1024);
  cvt_w_kernel<<<1024, 256, 0, stream>>>(opw,  opwb,  1024*1024);
  cvt_w_kernel<<<1024, 256, 0, stream>>>(pw,   pwb,   1024*1024);
  cvt_x_kernel<<<RPAD, 256, 0, stream>>>(x, xb);
  rope_tables_kernel<<<1, 512, 0, stream>>>(ctab, stab);
  argsort_kernel<<<dim3(B_, 6), 256, 0, stream>>>(ids, postab);

  // qkv = x @ qkv_w^T  (no bias), bf16 out
  gemm_kernel<<<dim3(RPAD/128, 3072/128), 256, 0, stream>>>(xb, 1024, qkvwb, nullptr, 1.f,
                                                            qkvb, nullptr, 3072, NROWS);
  // RoPE in place on q,k
  rope_kernel<<<(B_*NTOK*NH + 255)/256, 256, 0, stream>>>(qkvb, postab, ctab, stab);
  // in_proj merged: qp (*0.125*log2e folded), kp, vp
  gemm_inproj_kernel<<<dim3(RPAD/128, 8, 3), 256, 0, stream>>>(qkvb, ipwb, ipb, qpb, kpb, vpb);
  // V transpose into vt (aliases dead xb)
  vtrans_kernel<<<dim3(25, 16, 4), 256, 0, stream>>>(vpb, vtb);
  // attention
  attn_kernel<<<dim3(B_*NH, 13), 256, 0, stream>>>(qpb, kpb, vtb, ctxb);
  // out_proj then proj (final f32 to d_out)
  gemm_kernel<<<dim3(RPAD/128, 8), 256, 0, stream>>>(ctxb, 1024, opwb, opb, 1.f,
                                                     mhab, nullptr, 1024, NROWS);
  gemm_kernel<<<dim3(RPAD/128, 8), 256, 0, stream>>>(mhab, 1024, pwb,  pb,  1.f,
                                                     nullptr, out, 1024, NROWS);
}

// Round 10
// 390.232 us; speedup vs baseline: 1.1717x; 1.1714x over previous
//
#include <hip/hip_runtime.h>
#include <math.h>

#define B_ 4
#define NTOK 1537
#define NH 16
#define NROWS 6148      // B_*NTOK
#define RPAD 6272       // 49*128, padded rows
#define KDIM 1024
#define NKT 49          // key tiles of 32

typedef __attribute__((ext_vector_type(8))) short short8;
typedef __attribute__((ext_vector_type(4))) float f32x4;
typedef __attribute__((ext_vector_type(16))) float f32x16;
typedef __attribute__((ext_vector_type(4))) unsigned short ushort4v;
typedef __attribute__((ext_vector_type(4))) unsigned int uint4v;
typedef __attribute__((ext_vector_type(2))) unsigned int uint2v;

__device__ __forceinline__ float bf2f(unsigned short u){
  unsigned int x = ((unsigned int)u) << 16;
  return __uint_as_float(x);
}
__device__ __forceinline__ unsigned short f2bf(float f){
  unsigned int x = __float_as_uint(f);
  x += 0x7fff + ((x >> 16) & 1);   // RNE
  return (unsigned short)(x >> 16);
}
__device__ __forceinline__ unsigned int pack_bf16(float lo, float hi){
  return (unsigned int)f2bf(lo) | ((unsigned int)f2bf(hi) << 16);
}
// pack two f32 -> bf16 pair via round-half-up + byte-perm (3 ops)
__device__ __forceinline__ unsigned int pack_bf16_fast(float lo, float hi){
  unsigned int ue = __float_as_uint(lo) + 0x8000u;
  unsigned int uo = __float_as_uint(hi) + 0x8000u;
  return __builtin_amdgcn_perm(uo, ue, 0x07060302u);  // D = [uo.hi16, ue.hi16]
}
// native v_exp_f32: computes 2^x
__device__ __forceinline__ float fast_exp2(float x){
  return __builtin_amdgcn_exp2f(x);
}
// v_permlane32_swap_b32: returns ( {a.lo32lanes, b.lo32lanes}, {a.hi32lanes, b.hi32lanes} )
__device__ __forceinline__ uint2v permswap(unsigned int a, unsigned int b){
  return __builtin_amdgcn_permlane32_swap(a, b, false, false);
}
__device__ __forceinline__ void gload_lds16(const void* g, void* l){
  __builtin_amdgcn_global_load_lds((const __attribute__((address_space(1))) unsigned int*)g,
                                   (__attribute__((address_space(3))) unsigned int*)l, 16, 0, 0);
}
__device__ __forceinline__ f32x4 mfma16(short8 a, short8 b, f32x4 c){
  return __builtin_amdgcn_mfma_f32_16x16x32_bf16(a, b, c, 0, 0, 0);
}
__device__ __forceinline__ f32x16 mfma32(short8 a, short8 b, f32x16 c){
  return __builtin_amdgcn_mfma_f32_32x32x16_bf16(a, b, c, 0, 0, 0);
}

// ---------------- conversions ----------------
__global__ __launch_bounds__(256) void cvt_w_kernel(const float* __restrict__ src,
                                                    unsigned short* __restrict__ dst, int n){
  int i = (blockIdx.x*256 + threadIdx.x)*4;
  if (i >= n) return;
  f32x4 v = *(const f32x4*)(src + i);
  ushort4v o;
  #pragma unroll
  for (int j=0;j<4;j++) o[j] = f2bf(v[j]);
  *(ushort4v*)(dst + i) = o;
}

__global__ __launch_bounds__(256) void cvt_x_kernel(const float* __restrict__ x,
                                                    unsigned short* __restrict__ xb){
  size_t i = ((size_t)blockIdx.x*256 + threadIdx.x)*4;
  if (i >= (size_t)RPAD*KDIM) return;
  size_t row = i >> 10;
  ushort4v o;
  if (row < NROWS){
    f32x4 v = *(const f32x4*)(x + i);
    #pragma unroll
    for (int j=0;j<4;j++) o[j] = f2bf(v[j]);
  } else {
    o = (ushort4v)0;
  }
  *(ushort4v*)(xb + i) = o;
}

// ---------------- RoPE tables (pos 0..12, 32 freqs) ----------------
__global__ void rope_tables_kernel(float* __restrict__ ct, float* __restrict__ st){
  int i = threadIdx.x;
  if (i >= 13*32) return;
  int p = i >> 5, j = i & 31;
  float th = powf(10000.f, -(float)j * (1.f/32.f));
  float ang = (float)p * th;
  ct[i] = cosf(ang);
  st[i] = sinf(ang);
}

// ---------------- stable argsort -> pos table ----------------
// grid (B_, 6): each block ranks 256 elements of one batch.
__global__ __launch_bounds__(256) void argsort_kernel(const int* __restrict__ ids,
                                                      int* __restrict__ postab){
  __shared__ int vals[1536];
  int b = blockIdx.x;
  const int* src = ids + b*1536;
  for (int i=threadIdx.x; i<1536; i+=256) vals[i] = src[i];
  __syncthreads();
  int i = blockIdx.y*256 + threadIdx.x;
  int v = vals[i];
  int rank = 0;
  for (int j=0;j<1536;j++){
    int u = vals[j];
    rank += (u < v) || (u == v && j < i);   // stable rank
  }
  postab[b*1536 + rank] = (i % 12) + 1;     // (p % V) + 1
}

// ---------------- RoPE apply, in-place on bf16 qkv (q and k parts) ----------------
__global__ __launch_bounds__(256) void rope_kernel(unsigned short* __restrict__ qkv,
                                                   const int* __restrict__ postab,
                                                   const float* __restrict__ ct,
                                                   const float* __restrict__ st){
  int idx = blockIdx.x*256 + threadIdx.x;
  if (idx >= B_*NTOK*NH) return;
  int h = idx & 15;
  int bn = idx >> 4;
  int b = bn / NTOK;
  int n = bn - b*NTOK;
  unsigned short* rowp = qkv + (size_t)bn*3072;
  int pos = (n == 0) ? 0 : postab[b*1536 + (n-1)];
  const float* cr = ct + pos*32;
  const float* sr = st + pos*32;
  #pragma unroll
  for (int part=0; part<2; part++){
    unsigned short* p = rowp + part*1024 + h*64;
    uint4v vv[8];
    #pragma unroll
    for (int i=0;i<8;i++) vv[i] = ((const uint4v*)p)[i];
    unsigned short* tp = (unsigned short*)vv;
    unsigned short ov[64];
    if (n == 0){
      #pragma unroll
      for (int j=0;j<32;j++){ ov[j] = tp[2*j]; ov[32+j] = tp[2*j+1]; }
    } else {
      #pragma unroll
      for (int j=0;j<32;j++){
        float re = bf2f(tp[2*j]), im = bf2f(tp[2*j+1]);
        float c = cr[j], s = sr[j];
        ov[j]    = f2bf(re*c - im*s);
        ov[32+j] = f2bf(re*s + im*c);
      }
    }
    #pragma unroll
    for (int i=0;i<8;i++) ((uint4v*)p)[i] = ((const uint4v*)ov)[i];
  }
}

// ---------------- bf16 MFMA GEMM body: out[r][c] = (sum_k A[r][k]*W[c][k] + bias[c]) * scale
__device__ __forceinline__ void gemm_body(const unsigned short* __restrict__ A, int lda,
    const unsigned short* __restrict__ W,
    const float* __restrict__ bias, float scale,
    unsigned short* __restrict__ outb, float* __restrict__ outf, int ldo, int mvalid,
    int rowBase, int colBase)
{
  __shared__ alignas(16) unsigned short At[128][32];
  __shared__ alignas(16) unsigned short Bt[128][32];
  int t = threadIdx.x, w = t >> 6, lane = t & 63;
  int g = lane >> 4, l15 = lane & 15;
  int rb = (w >> 1) * 64, cb = (w & 1) * 64;
  f32x4 acc[4][4];
  #pragma unroll
  for (int m=0;m<4;m++)
    #pragma unroll
    for (int n=0;n<4;n++) acc[m][n] = 0.f;
  int srow = lane >> 2;            // 0..15
  int scol = (lane & 3) * 8;       // 0,8,16,24
  for (int kb = 0; kb < KDIM; kb += 32){
    __syncthreads();
    #pragma unroll
    for (int i=0;i<2;i++){
      int rr = i*64 + w*16 + srow;
      gload_lds16(A + (size_t)(rowBase + rr)*lda + kb + scol, &At[i*64 + w*16][0]);
      gload_lds16(W + (size_t)(colBase + rr)*KDIM + kb + scol, &Bt[i*64 + w*16][0]);
    }
    __syncthreads();
    short8 af[4], bf[4];
    #pragma unroll
    for (int m=0;m<4;m++) af[m] = *(const short8*)&At[rb + m*16 + l15][g*8];
    #pragma unroll
    for (int n=0;n<4;n++) bf[n] = *(const short8*)&Bt[cb + n*16 + l15][g*8];
    #pragma unroll
    for (int m=0;m<4;m++)
      #pragma unroll
      for (int n=0;n<4;n++)
        acc[m][n] = mfma16(af[m], bf[n], acc[m][n]);
  }
  #pragma unroll
  for (int m=0;m<4;m++)
    #pragma unroll
    for (int n=0;n<4;n++){
      int col = colBase + cb + n*16 + l15;
      float bv = bias ? bias[col] : 0.f;
      #pragma unroll
      for (int r=0;r<4;r++){
        int row = rowBase + rb + m*16 + g*4 + r;
        if (row < mvalid){
          float v = (acc[m][n][r] + bv) * scale;
          if (outf) outf[(size_t)row*ldo + col] = v;
          else      outb[(size_t)row*ldo + col] = f2bf(v);
        }
      }
    }
}

__global__ __launch_bounds__(256) void gemm_kernel(const unsigned short* __restrict__ A, int lda,
    const unsigned short* __restrict__ W,
    const float* __restrict__ bias, float scale,
    unsigned short* __restrict__ outb, float* __restrict__ outf, int ldo, int mvalid)
{
  gemm_body(A, lda, W, bias, scale, outb, outf, ldo, mvalid,
            blockIdx.x*128, blockIdx.y*128);
}

// merged in_proj: z = 0,1,2 -> q,k,v
// q scale folds 1/sqrt(64) AND log2(e) (softmax runs in exp2 domain).
__global__ __launch_bounds__(256) void gemm_inproj_kernel(const unsigned short* __restrict__ qkvb,
    const unsigned short* __restrict__ ipwb, const float* __restrict__ ipb,
    unsigned short* __restrict__ qpb, unsigned short* __restrict__ kpb,
    unsigned short* __restrict__ vpb)
{
  int z = blockIdx.z;
  const unsigned short* A = qkvb + z*1024;
  const unsigned short* W = ipwb + (size_t)z*1024*1024;
  const float* bias = ipb + z*1024;
  float scale = (z == 0) ? 0.125f*1.44269504f : 1.f;
  unsigned short* outb = (z == 0) ? qpb : (z == 1 ? kpb : vpb);
  gemm_body(A, 3072, W, bias, scale, outb, nullptr, 1024, NROWS,
            blockIdx.x*128, blockIdx.y*128);
}

// ---------------- K fragments: kf[(bh*NKT+kt)*2048 + c*512 + lane*8]
// = K[key = kt*32 + (lane&31) clamped][d = c*16 + (lane>>5)*8 .. +8]   (coalesced for attn)
__global__ __launch_bounds__(256) void kfrag_kernel(const unsigned short* __restrict__ kp,
                                                    unsigned short* __restrict__ kf){
  int bh = blockIdx.x, kt = blockIdx.y;
  int b = bh >> 4, h = bh & 15;
  int t = threadIdx.x;
  int lane = t & 63, c = t >> 6;
  int l31 = lane & 31, hh = lane >> 5;
  int key = kt*32 + l31; if (key > NTOK-1) key = NTOK-1;
  uint4v v = *(const uint4v*)(kp + (size_t)(b*NTOK + key)*KDIM + h*64 + c*16 + hh*8);
  *(uint4v*)(kf + (size_t)(bh*NKT + kt)*2048 + c*512 + lane*8) = v;
}

// ---------------- V fragments: vf[(bh*NKT+kt)*2048 + w*512 + lane*8], w = dblk*2 + c
// elem j = V[key = kt*32 + c*16 + (lane>>5)*8 + j][d = dblk*32 + (lane&31)], zero past NTOK
__global__ __launch_bounds__(256) void vfrag_kernel(const unsigned short* __restrict__ vp,
                                                    unsigned short* __restrict__ vf){
  __shared__ alignas(16) unsigned short Tl[32][72];
  int bh = blockIdx.x, kt = blockIdx.y;
  int b = bh >> 4, h = bh & 15;
  int t = threadIdx.x;
  {
    int r = t >> 3, ch = t & 7;
    int key = kt*32 + r;
    uint4v v;
    if (key < NTOK){
      v = *(const uint4v*)(vp + (size_t)(b*NTOK + key)*KDIM + h*64 + ch*8);
    } else v = (uint4v)0;
    *(uint4v*)&Tl[r][ch*8] = v;
  }
  __syncthreads();
  {
    int lane = t & 63, w = t >> 6;     // w = dblk*2 + c
    int l31 = lane & 31, hh = lane >> 5;
    int dblk = w >> 1, c = w & 1;
    unsigned short ov[8];
    #pragma unroll
    for (int j=0;j<8;j++) ov[j] = Tl[c*16 + hh*8 + j][dblk*32 + l31];
    *(uint4v*)(vf + (size_t)(bh*NKT + kt)*2048 + w*512 + lane*8) = *(const uint4v*)ov;
  }
}

// ---------------- flash attention, 32x32x16 MFMA, swapped operands, zero LDS,
// 2-deep pipeline, exp2 softmax, permlane cross-lane, fragment-order COALESCED loads.
// grid (B*H, 13); 4 waves, each owns 32 q rows.
__global__ __launch_bounds__(256) void attn_kernel(const unsigned short* __restrict__ qp,
    const unsigned short* __restrict__ kf, const unsigned short* __restrict__ vf,
    unsigned short* __restrict__ ctx)
{
  int bh = blockIdx.x;
  int qt = blockIdx.y;
  int b = bh >> 4, hd = bh & 15;
  int t = threadIdx.x, w = t >> 6, lane = t & 63;
  int l31 = lane & 31, hh = lane >> 5;
  int qrow = qt*128 + w*32 + l31;
  int qcl = qrow > NTOK-1 ? NTOK-1 : qrow;
  const unsigned short* qb = qp + (((size_t)(b*NTOK + qcl)*NH + hd) << 6) + hh*8;
  short8 qf[4];
  #pragma unroll
  for (int c=0;c<4;c++) qf[c] = *(const short8*)(qb + c*16);
  const unsigned short* kfb = kf + (size_t)(bh*NKT)*2048 + lane*8;
  const unsigned short* vfb = vf + (size_t)(bh*NKT)*2048 + lane*8;
  float m_ = -3e38f, l_ = 0.f;   // l_ is a PER-HALF partial sum; reduced once at the end
  f32x16 o0 = 0.f, o1 = 0.f;

  auto soft_pv = [&](f32x16 cc, short8 va00, short8 va01, short8 va10, short8 va11){
    float t0 = fmaxf(fmaxf(cc[0],cc[1]), fmaxf(cc[2],cc[3]));
    float t1 = fmaxf(fmaxf(cc[4],cc[5]), fmaxf(cc[6],cc[7]));
    float t2 = fmaxf(fmaxf(cc[8],cc[9]), fmaxf(cc[10],cc[11]));
    float t3 = fmaxf(fmaxf(cc[12],cc[13]), fmaxf(cc[14],cc[15]));
    float mx = fmaxf(fmaxf(t0,t1), fmaxf(t2,t3));
    {   // cross-half max via permlane (VALU, no DS)
      uint2v pr = permswap(__float_as_uint(mx), __float_as_uint(mx));
      mx = fmaxf(__uint_as_float(pr[0]), __uint_as_float(pr[1]));
    }
    // defer-max (T13): 11.5 log2-units ~= 8 nats; P bounded by 2^11.5
    if (!__all(mx <= m_ + 11.5f)){
      float mn = fmaxf(m_, mx);
      float al = fast_exp2(m_ - mn);
      m_ = mn;
      l_ *= al;
      #pragma unroll
      for (int i=0;i<16;i++){ o0[i] *= al; o1[i] *= al; }
    }
    float p[16], rs = 0.f;
    #pragma unroll
    for (int i=0;i<16;i++){ p[i] = fast_exp2(cc[i] - m_); }
    #pragma unroll
    for (int i=0;i<16;i++) rs += p[i];
    l_ += rs;   // per-half partial (m_ is synchronized across halves)
    unsigned int W[8];
    #pragma unroll
    for (int wd=0; wd<8; wd++) W[wd] = pack_bf16_fast(p[2*wd], p[2*wd+1]);
    // cross-half exchange via permlane32_swap
    uint2v e0 = permswap(W[0], W[2]);
    uint2v e1 = permswap(W[1], W[3]);
    uint2v e2 = permswap(W[4], W[6]);
    uint2v e3 = permswap(W[5], W[7]);
    uint4v u0, u1;
    u0[0]=e0[0]; u0[1]=e1[0]; u0[2]=e0[1]; u0[3]=e1[1];
    u1[0]=e2[0]; u1[1]=e3[0]; u1[2]=e2[1]; u1[3]=e3[1];
    short8 pb0, pb1;
    __builtin_memcpy(&pb0, &u0, 16);
    __builtin_memcpy(&pb1, &u1, 16);
    o0 = mfma32(va00, pb0, o0);
    o0 = mfma32(va01, pb1, o0);
    o1 = mfma32(va10, pb0, o1);
    o1 = mfma32(va11, pb1, o1);
  };

  // prologue: cc(tile 0), K(tile 1) in flight
  short8 ka[4];
  #pragma unroll
  for (int c=0;c<4;c++) ka[c] = *(const short8*)(kfb + c*512);
  f32x16 cc = 0.f;
  cc = mfma32(ka[0], qf[0], cc);
  cc = mfma32(ka[1], qf[1], cc);
  cc = mfma32(ka[2], qf[2], cc);
  cc = mfma32(ka[3], qf[3], cc);
  #pragma unroll
  for (int c=0;c<4;c++) ka[c] = *(const short8*)(kfb + 2048 + c*512);

  for (int kt=0; kt<48; ++kt){
    // V for tile kt, issued first (coalesced fragment loads)
    const unsigned short* vB = vfb + (size_t)kt*2048;
    short8 va00 = *(const short8*)(vB);
    short8 va01 = *(const short8*)(vB + 512);
    short8 va10 = *(const short8*)(vB + 1024);
    short8 va11 = *(const short8*)(vB + 1536);
    // QK^T for tile kt+1 — runs in the MFMA pipe during soft_pv(kt)'s VALU work
    f32x16 cn = 0.f;
    cn = mfma32(ka[0], qf[0], cn);
    cn = mfma32(ka[1], qf[1], cn);
    cn = mfma32(ka[2], qf[2], cn);
    cn = mfma32(ka[3], qf[3], cn);
    // prefetch K for tile kt+2 (clamped to last tile)
    int ktn = kt+2 < NKT-1 ? kt+2 : NKT-1;
    const unsigned short* kB = kfb + (size_t)ktn*2048;
    #pragma unroll
    for (int c=0;c<4;c++) ka[c] = *(const short8*)(kB + c*512);
    soft_pv(cc, va00, va01, va10, va11);
    cc = cn;
  }
  // tail tile 48: only key 1536 valid -> (reg 0, hh 0)
  {
    const unsigned short* vB = vfb + (size_t)48*2048;
    short8 va00 = *(const short8*)(vB);
    short8 va01 = *(const short8*)(vB + 512);
    short8 va10 = *(const short8*)(vB + 1024);
    short8 va11 = *(const short8*)(vB + 1536);
    #pragma unroll
    for (int i=0;i<16;i++) cc[i] = (i == 0 && hh == 0) ? cc[i] : -1e30f;
    soft_pv(cc, va00, va01, va10, va11);
  }
  // final cross-half l reduce (the only one in the kernel)
  {
    uint2v pr = permswap(__float_as_uint(l_), __float_as_uint(l_));
    l_ = __uint_as_float(pr[0]) + __uint_as_float(pr[1]);
  }
  // write: o{0,1}[reg] -> ctx[q=l31][d = dblk*32 + 8*(reg>>2) + 4*hh + (reg&3)]
  if (qrow < NTOK){
    float inv = 1.f / l_;
    unsigned short* cb = ctx + (((size_t)(b*NTOK + qrow)*NH + hd) << 6) + 4*hh;
    #pragma unroll
    for (int s=0;s<4;s++){
      uint2v u;
      u[0] = pack_bf16(o0[4*s]*inv,   o0[4*s+1]*inv);
      u[1] = pack_bf16(o0[4*s+2]*inv, o0[4*s+3]*inv);
      *(uint2v*)(cb + 8*s) = u;
    }
    #pragma unroll
    for (int s=0;s<4;s++){
      uint2v u;
      u[0] = pack_bf16(o1[4*s]*inv,   o1[4*s+1]*inv);
      u[1] = pack_bf16(o1[4*s+2]*inv, o1[4*s+3]*inv);
      *(uint2v*)(cb + 32 + 8*s) = u;
    }
  }
}

extern "C" void kernel_launch(void* const* d_in, const int* in_sizes, int n_in,
                              void* d_out, int out_size, void* d_ws, size_t ws_size,
                              hipStream_t stream)
{
  const float* x    = (const float*)d_in[0];
  const float* qkvw = (const float*)d_in[1];
  const float* ipw  = (const float*)d_in[2];
  const float* ipb  = (const float*)d_in[3];
  const float* opw  = (const float*)d_in[4];
  const float* opb  = (const float*)d_in[5];
  const float* pw   = (const float*)d_in[6];
  const float* pb   = (const float*)d_in[7];
  const int*   ids  = (const int*)d_in[8];
  float* out = (float*)d_out;

  char* p = (char*)d_ws;
  auto alloc = [&](size_t bytes)->char* {
    char* r = p; p += (bytes + 255) & ~(size_t)255; return r;
  };
  unsigned short* xb    = (unsigned short*)alloc((size_t)RPAD*1024*2);   // reused as vf
  unsigned short* qkvwb = (unsigned short*)alloc((size_t)3072*1024*2);
  unsigned short* ipwb  = (unsigned short*)alloc((size_t)3072*1024*2);
  unsigned short* opwb  = (unsigned short*)alloc((size_t)1024*1024*2);
  unsigned short* pwb   = (unsigned short*)alloc((size_t)1024*1024*2);
  unsigned short* qkvb  = (unsigned short*)alloc((size_t)RPAD*3072*2);   // reused as kf
  unsigned short* qpb   = (unsigned short*)alloc((size_t)RPAD*1024*2);
  unsigned short* kpb   = (unsigned short*)alloc((size_t)RPAD*1024*2);
  unsigned short* vpb   = (unsigned short*)alloc((size_t)RPAD*1024*2);
  unsigned short* ctxb  = (unsigned short*)alloc((size_t)RPAD*1024*2);
  unsigned short* mhab  = (unsigned short*)alloc((size_t)RPAD*1024*2);
  int*   postab = (int*)alloc((size_t)B_*1536*4);
  float* ctab   = (float*)alloc(13*32*4);
  float* stab   = (float*)alloc(13*32*4);
  unsigned short* vfb = xb;     // 64*49*2048*2 = 12,845,056 B == xb size exactly
  unsigned short* kfb = qkvb;   // 12.85 MB into qkvb's 38.5 MB (dead after inproj)

  cvt_w_kernel<<<3072, 256, 0, stream>>>(qkvw, qkvwb, 3072*1024);
  cvt_w_kernel<<<3072, 256, 0, stream>>>(ipw,  ipwb,  3072*1024);
  cvt_w_kernel<<<1024, 256, 0, stream>>>(opw,  opwb,  1024*1024);
  cvt_w_kernel<<<1024, 256, 0, stream>>>(pw,   pwb,   1024*1024);
  cvt_x_kernel<<<RPAD, 256, 0, stream>>>(x, xb);
  rope_tables_kernel<<<1, 512, 0, stream>>>(ctab, stab);
  argsort_kernel<<<dim3(B_, 6), 256, 0, stream>>>(ids, postab);

  // qkv = x @ qkv_w^T  (no bias), bf16 out
  gemm_kernel<<<dim3(RPAD/128, 3072/128), 256, 0, stream>>>(xb, 1024, qkvwb, nullptr, 1.f,
                                                            qkvb, nullptr, 3072, NROWS);
  // RoPE in place on q,k
  rope_kernel<<<(B_*NTOK*NH + 255)/256, 256, 0, stream>>>(qkvb, postab, ctab, stab);
  // in_proj merged: qp (*0.125*log2e folded), kp, vp
  gemm_inproj_kernel<<<dim3(RPAD/128, 8, 3), 256, 0, stream>>>(qkvb, ipwb, ipb, qpb, kpb, vpb);
  // fragment-order K and V (coalesced attn loads); xb and qkvb are dead now
  kfrag_kernel<<<dim3(B_*NH, NKT), 256, 0, stream>>>(kpb, kfb);
  vfrag_kernel<<<dim3(B_*NH, NKT), 256, 0, stream>>>(vpb, vfb);
  // attention
  attn_kernel<<<dim3(B_*NH, 13), 256, 0, stream>>>(qpb, kfb, vfb, ctxb);
  // out_proj then proj (final f32 to d_out)
  gemm_kernel<<<dim3(RPAD/128, 8), 256, 0, stream>>>(ctxb, 1024, opwb, opb, 1.f,
                                                     mhab, nullptr, 1024, NROWS);
  gemm_kernel<<<dim3(RPAD/128, 8), 256, 0, stream>>>(mhab, 1024, pwb,  pb,  1.f,
                                                     nullptr, out, 1024, NROWS);
}